// Round 3
// baseline (33274.158 us; speedup 1.0000x reference)
//
#include <hip/hip_runtime.h>
#include <cfloat>
#include <math.h>

#define N 512
#define NW 8   // columns per lane (64 lanes x 8 = 512)

__device__ __forceinline__ unsigned long long map_f64(double x) {
    unsigned long long b = (unsigned long long)__double_as_longlong(x);
    return b ^ ((b >> 63) ? 0xFFFFFFFFFFFFFFFFull : 0x8000000000000000ull);
}
__device__ __forceinline__ double unmap_f64(unsigned long long b) {
    b ^= ((b >> 63) ? 0x8000000000000000ull : 0xFFFFFFFFFFFFFFFFull);
    return __longlong_as_double((long long)b);
}

// Precompute numpy-bit-exact f64 cost matrix C[i][j] (IEEE sqrt, contract off).
__global__ void cost_kernel(const float* __restrict__ dgm,
                            const float* __restrict__ dgm_x,
                            double* __restrict__ C) {
#pragma clang fp contract(off)
    const int i = blockIdx.x;
    const double bi = (double)dgm[2 * i], di = (double)dgm[2 * i + 1];
    double* row = C + (size_t)i * N;
    for (int s = 0; s < NW; ++s) {
        const int j = s * 64 + threadIdx.x;
        const double db = bi - (double)dgm_x[2 * j];
        const double dd = di - (double)dgm_x[2 * j + 1];
        row[j] = sqrt(db * db + dd * dd);
    }
}

// Single-wave exact JV solver: 64 lanes, lane owns cols lane*8+1..lane*8+8.
// Warm start: column reduction + greedy tight matching + LAPJV augmenting
// row reduction (all invariant-preserving), then exact Dijkstra phase.
__global__ __launch_bounds__(64, 1) void solve_kernel(
    const double* __restrict__ C,
    const float* __restrict__ dgm, const float* __restrict__ dgm_x,
    float* __restrict__ out)
{
#pragma clang fp contract(off)
    __shared__ double u_lds[N + 1];
    __shared__ int    p_lds[N + 1];
    __shared__ int    way_lds[N + 1];
    __shared__ int    claim[N + 1];
    __shared__ int    flist[4 * N + 32];
    __shared__ unsigned long long slot[2];
    __shared__ int nfree_s;

    const int lane = threadIdx.x;          // 0..63
    double v[NW], minv[NW], du[NW];
    int pcol[NW], amin[NW];

    for (int s = 0; s < NW; ++s) {
        const int k = lane * NW + s + 1;
        u_lds[k] = 0.0; p_lds[k] = 0; way_lds[k] = 0; claim[k] = 0x7fffffff;
    }
    if (lane == 0) { u_lds[0] = 0.0; p_lds[0] = 0; way_lds[0] = 0;
                     claim[0] = 0x7fffffff; slot[0] = ~0ull; slot[1] = ~0ull; }
    __syncthreads();

    // ---- column reduction: v[j] = min_i C[i][j] (warms L2 with the matrix) ----
    for (int s = 0; s < NW; ++s) { v[s] = DBL_MAX; amin[s] = 1; }
    {
        const double* base = C + lane * NW;
        #pragma unroll 4
        for (int i = 0; i < N; ++i) {
            const double* row = base + (size_t)i * N;
            #pragma unroll
            for (int s = 0; s < NW; ++s) {
                const double c = row[s];
                if (c < v[s]) { v[s] = c; amin[s] = i + 1; }
            }
        }
    }

    // ---- greedy tight matching: row r goes to smallest col with argmin r ----
    for (int s = 0; s < NW; ++s)
        atomicMin(&claim[amin[s]], lane * NW + s + 1);
    __syncthreads();
    for (int s = 0; s < NW; ++s) {
        const int col = lane * NW + s + 1;
        if (claim[amin[s]] == col) p_lds[col] = amin[s];
    }
    __syncthreads();
    // build freelist of unmatched rows
    for (int s = 0; s < NW; ++s) claim[lane * NW + s + 1] = 0;
    __syncthreads();
    for (int s = 0; s < NW; ++s) {
        const int r = p_lds[lane * NW + s + 1];
        if (r) claim[r] = 1;
    }
    __syncthreads();
    if (lane == 0) {
        int nf = 0;
        for (int r = 1; r <= N; ++r) if (!claim[r]) flist[nf++] = r;
        nfree_s = nf;
    }
    __syncthreads();

    // ---- augmenting row reduction (LAPJV): invariant-preserving, step-capped --
    {
        int head = 0, tail = nfree_s;
        const int cap = 3 * tail + 16;
        for (int step = 0; step < cap && head < tail; ++step) {
            const int i = flist[head++];
            const double* row = C + (size_t)(i - 1) * N + lane * NW;
            double v1 = DBL_MAX, m2 = DBL_MAX; int j1 = N + 1;
            #pragma unroll
            for (int s = 0; s < NW; ++s) {
                const double val = row[s] - v[s];
                const int col = lane * NW + s + 1;
                if (val < v1 || (val == v1 && col < j1)) { m2 = v1; v1 = val; j1 = col; }
                else if (val < m2) m2 = val;
            }
            #pragma unroll
            for (int m = 32; m >= 1; m >>= 1) {     // exact (f64) pair reduce
                const double ov1 = __shfl_xor(v1, m, 64);
                const double om2 = __shfl_xor(m2, m, 64);
                const int    oj1 = __shfl_xor(j1, m, 64);
                if (ov1 < v1 || (ov1 == v1 && oj1 < j1)) {
                    m2 = fmin(v1, fmin(om2, m2));
                    v1 = ov1; j1 = oj1;
                } else {
                    m2 = fmin(m2, fmin(ov1, om2));
                }
            }
            const int k_old = p_lds[j1];            // uniform read, pre-write
            if (((j1 - 1) >> 3) == lane && m2 > v1) v[(j1 - 1) & 7] -= (m2 - v1);
            if (lane == 0) {
                u_lds[i] = m2;                      // feasible: val>=m2 for j!=j1, tight on j1
                p_lds[j1] = i;
                if (k_old) flist[tail] = k_old;     // displaced row re-queued
            }
            if (k_old) ++tail;                      // uniform
            __syncthreads();
        }
    }

    // ---- rebuild freelist from p (robust vs ARR cap/edge cases) ----
    for (int s = 0; s < NW; ++s) claim[lane * NW + s + 1] = 0;
    __syncthreads();
    for (int s = 0; s < NW; ++s) {
        const int r = p_lds[lane * NW + s + 1];
        if (r) claim[r] = 1;
    }
    __syncthreads();
    if (lane == 0) {
        int nf = 0;
        for (int r = 1; r <= N; ++r) if (!claim[r]) flist[nf++] = r;
        nfree_s = nf;
    }
    __syncthreads();
    const int nfree = nfree_s;

    // ---- exact Dijkstra phase ----
    for (int kk = 0; kk < nfree; ++kk) {
        const int iroot = flist[kk];
        #pragma unroll
        for (int s = 0; s < NW; ++s) {
            pcol[s] = p_lds[lane * NW + s + 1];   // static during this Dijkstra
            minv[s] = DBL_MAX;
            du[s] = 0.0;
        }
        double du0 = 0.0;
        if (lane == 0) p_lds[0] = iroot;          // augment-chain terminator
        __syncthreads();

        int i0 = iroot, juse = 0, par = 0, used = 0;
        while (true) {
            if (juse) {                            // mark prev winner used
                const int sl = juse - 1 - lane * NW;
                if ((unsigned)sl < NW) used |= (1 << sl);
            }
            const double* row = C + (size_t)(i0 - 1) * N + lane * NW;
            double c8[NW];
            #pragma unroll
            for (int s = 0; s < NW; ++s) c8[s] = row[s];   // L2-hit loads, issued early
            const double u_i0 = u_lds[i0];
            unsigned long long kbest = ~0ull;
            #pragma unroll
            for (int s = 0; s < NW; ++s) {
                if (!((used >> s) & 1)) {
                    const double cur = (c8[s] - u_i0) - v[s];
                    if (cur < minv[s]) { minv[s] = cur; way_lds[lane * NW + s + 1] = juse; }
                    // key: [45b value | 9b col-1 | 10b p[col]]
                    const unsigned long long k =
                        (map_f64(minv[s]) & ~0x7FFFFull)
                        | ((unsigned long long)(lane * NW + s) << 10)
                        | (unsigned long long)pcol[s];
                    if (k < kbest) kbest = k;
                }
            }
            atomicMin(&slot[par], kbest);          // same-address ds_min_u64 reduce
            __syncthreads();                       // 1-wave barrier: cheap
            const unsigned long long key = slot[par];
            if (lane == 0) slot[par] = ~0ull;      // reset for use 2 iters later
            par ^= 1;
            const double delta = unmap_f64(key & ~0x7FFFFull);  // <= all true minv
            #pragma unroll
            for (int s = 0; s < NW; ++s) {
                if ((used >> s) & 1) { v[s] -= delta; du[s] += delta; }
                else                 { minv[s] -= delta; }
            }
            if (lane == 0) du0 += delta;
            juse = (int)((key >> 10) & 511) + 1;
            i0   = (int)(key & 1023);              // p[j1] payload; 0 => augment
            if (i0 == 0) break;
        }
        // flush register-accumulated duals (distinct rows -> race-free)
        #pragma unroll
        for (int s = 0; s < NW; ++s)
            if ((used >> s) & 1) u_lds[pcol[s]] += du[s];
        if (lane == 0) {
            u_lds[iroot] += du0;
            int j = juse;                          // augment (path is short)
            while (j) { const int jn = way_lds[j]; p_lds[j] = p_lds[jn]; j = jn; }
        }
        __syncthreads();
    }

    // ---- loss ----
    double acc = 0.0;
    for (int s = 0; s < NW; ++s) {
        const int j = lane * NW + s;
        const int r = p_lds[j + 1] - 1;
        const float fb = dgm[2 * r]     - dgm_x[2 * j];
        const float fd = dgm[2 * r + 1] - dgm_x[2 * j + 1];
        acc += (double)fb * (double)fb + (double)fd * (double)fd;
    }
    #pragma unroll
    for (int m = 32; m >= 1; m >>= 1) acc += __shfl_xor(acc, m, 64);
    if (lane == 0) out[0] = (float)(0.5 * acc);
}

// ---------- Round-2 fallback (used only if ws_size < 2 MB) ----------
__global__ __launch_bounds__(512, 1) void tofu_fallback(
    const float* __restrict__ dgm, const float* __restrict__ dgm_x,
    float* __restrict__ out)
{
#pragma clang fp contract(off)
    __shared__ double b_lds[N];
    __shared__ double d_lds[N];
    __shared__ double u_lds[N + 1];
    __shared__ int    p_lds[N + 1];
    __shared__ int    way_lds[N + 1];
    __shared__ int    argmin_lds[N + 1];
    __shared__ int    freelist[N];
    __shared__ int    nfree_s;
    __shared__ unsigned long long part[2][8];
    __shared__ double red8[8];

    const int tid  = threadIdx.x;
    const int col  = tid + 1;
    const int lane = tid & 63;
    const int wid  = tid >> 6;

    b_lds[tid] = (double)dgm[2 * tid];
    d_lds[tid] = (double)dgm[2 * tid + 1];
    const double xb = (double)dgm_x[2 * tid];
    const double xd = (double)dgm_x[2 * tid + 1];
    u_lds[col] = 0.0; p_lds[col] = 0; way_lds[col] = 0;
    if (tid == 0) { u_lds[0] = 0.0; p_lds[0] = 0; way_lds[0] = 0; }
    __syncthreads();

    double v_j = DBL_MAX; int imin = 0;
    for (int i = 0; i < N; ++i) {
        const double db = b_lds[i] - xb;
        const double dd = d_lds[i] - xd;
        const double c  = sqrt(db * db + dd * dd);
        if (c < v_j) { v_j = c; imin = i; }
    }
    argmin_lds[col] = imin + 1;
    __syncthreads();

    if (tid == 0) {
        for (int j = 1; j <= N; ++j) {
            const int r = argmin_lds[j];
            if (!way_lds[r]) { way_lds[r] = 1; p_lds[j] = r; }
        }
        int nf = 0;
        for (int r = 1; r <= N; ++r) if (!way_lds[r]) freelist[nf++] = r;
        nfree_s = nf;
    }
    __syncthreads();
    const int nfree = nfree_s;

    for (int kk = 0; kk < nfree; ++kk) {
        __syncthreads();
        const int i = freelist[kk];
        const int p_own = p_lds[col];
        if (tid == 0) p_lds[0] = i;

        double minv = DBL_MAX;
        bool   used = false;
        double du = 0.0, du0 = 0.0;
        int j0 = 0, i0 = i, par = 0;

        while (true) {
            if (col == j0) used = true;
            const double u_i0 = u_lds[i0];
            if (!used) {
                const double db = b_lds[i0 - 1] - xb;
                const double dd = d_lds[i0 - 1] - xd;
                const double c  = sqrt(db * db + dd * dd);
                const double cur = (c - u_i0) - v_j;
                if (cur < minv) { minv = cur; way_lds[col] = j0; }
            }
            unsigned long long key = used ? 0xFFFFFFFFFFFFFFFFull
                : ((map_f64(minv) & ~511ull) | (unsigned long long)(col - 1));
            #pragma unroll
            for (int off = 32; off >= 1; off >>= 1) {
                const unsigned long long o = __shfl_down(key, off, 64);
                if (o < key) key = o;
            }
            if (lane == 0) part[par][wid] = key;
            __syncthreads();
            unsigned long long km = part[par][0];
            #pragma unroll
            for (int w = 1; w < 8; ++w) {
                const unsigned long long o = part[par][w];
                if (o < km) km = o;
            }
            const int j1 = (int)(km & 511ull) + 1;
            const double delta = unmap_f64(km & ~511ull);

            if (used) { v_j -= delta; du += delta; }
            else      { minv -= delta; }
            if (tid == 0) du0 += delta;

            j0 = j1;
            i0 = p_lds[j1];
            par ^= 1;
            if (i0 == 0) break;
        }

        __syncthreads();
        if (used) u_lds[p_own] += du;
        if (tid == 0) {
            u_lds[i] += du0;
            int j = j0;
            while (j) { const int jn = way_lds[j]; p_lds[j] = p_lds[jn]; j = jn; }
        }
    }
    __syncthreads();

    const int r = p_lds[col] - 1;
    const float fb = dgm[2 * r]     - dgm_x[2 * tid];
    const float fd = dgm[2 * r + 1] - dgm_x[2 * tid + 1];
    double contrib = (double)fb * (double)fb + (double)fd * (double)fd;
    #pragma unroll
    for (int off = 32; off >= 1; off >>= 1)
        contrib += __shfl_down(contrib, off, 64);
    if (lane == 0) red8[wid] = contrib;
    __syncthreads();
    if (tid == 0) {
        double s = 0.0;
        #pragma unroll
        for (int w = 0; w < 8; ++w) s += red8[w];
        out[0] = (float)(0.5 * s);
    }
}

extern "C" void kernel_launch(void* const* d_in, const int* in_sizes, int n_in,
                              void* d_out, int out_size, void* d_ws, size_t ws_size,
                              hipStream_t stream) {
    const float* dgm   = (const float*)d_in[0];
    const float* dgm_x = (const float*)d_in[1];
    float* out = (float*)d_out;
    const size_t need = (size_t)N * N * sizeof(double);
    if (ws_size >= need) {
        double* C = (double*)d_ws;
        cost_kernel<<<N, 64, 0, stream>>>(dgm, dgm_x, C);
        solve_kernel<<<1, 64, 0, stream>>>(C, dgm, dgm_x, out);
    } else {
        tofu_fallback<<<1, 512, 0, stream>>>(dgm, dgm_x, out);
    }
}